// Round 1
// baseline (1155.833 us; speedup 1.0000x reference)
//
#include <hip/hip_runtime.h>
#include <hip/hip_bf16.h>
#include <cstdint>
#include <cstddef>

#define Bsz  256
#define Tn   4096
#define In   8
#define Hn   32
#define Gn   96
#define TGTn 8
#define CH   256   // timesteps per staged chunk

__device__ __forceinline__ float rcpf(float x) { return __builtin_amdgcn_rcpf(x); }
__device__ __forceinline__ float sigm(float x) { return rcpf(1.f + __expf(-x)); }
__device__ __forceinline__ float tanhfast(float x) {
    float e = __expf(2.f * x);            // saturates correctly for |x| large
    return 1.f - 2.f * rcpf(e + 1.f);
}

// W = w_ih @ E : [96,8]
__global__ void fuse_wih_kernel(const float* __restrict__ w_ih,
                                const float* __restrict__ E,
                                float* __restrict__ Wf) {
    int tid = threadIdx.x;                // 768 threads
    int g = tid >> 3, i = tid & 7;
    float acc = 0.f;
#pragma unroll
    for (int k = 0; k < Hn; ++k)
        acc = fmaf(w_ih[g * Hn + k], E[k * In + i], acc);
    Wf[g * In + i] = acc;
}

// One block = one batch element, one wave (64 lanes).
// lane = grp*32 + j : owns gate rows {j, 32+j, 64+j}, K-half grp.
__launch_bounds__(64, 1)
__global__ void gru_kernel(const float* __restrict__ x,     // [B,T,8]
                           const float* __restrict__ Wf,    // [96,8] fused w_ih@E
                           const float* __restrict__ w_hh,  // [96,32]
                           const float* __restrict__ b_ih,  // [96]
                           const float* __restrict__ b_hh,  // [96]
                           float* __restrict__ latents) {   // [B,T,32]
    __shared__ __align__(16) float lds_h[Hn];
    __shared__ __align__(16) float lds_x[CH * In];     // 8 KB
    __shared__ __align__(16) float lds_lat[CH * Hn];   // 32 KB

    const int lane = threadIdx.x;
    const int grp  = lane >> 5;     // which K-half (0: k/i low, 1: high)
    const int j    = lane & 31;     // hidden index this lane produces
    const int b    = blockIdx.x;

    const float* xb  = x + (size_t)b * Tn * In;
    float* latb      = latents + (size_t)b * Tn * Hn;

    // recurrent weights, 16 K-elements per gate per lane (48 VGPRs)
    float whr[16], whz[16], whn[16];
#pragma unroll
    for (int q = 0; q < 4; ++q) {
        float4 vr = *(const float4*)&w_hh[(0 * Hn + j) * Hn + grp * 16 + q * 4];
        float4 vz = *(const float4*)&w_hh[(1 * Hn + j) * Hn + grp * 16 + q * 4];
        float4 vn = *(const float4*)&w_hh[(2 * Hn + j) * Hn + grp * 16 + q * 4];
        whr[q*4+0] = vr.x; whr[q*4+1] = vr.y; whr[q*4+2] = vr.z; whr[q*4+3] = vr.w;
        whz[q*4+0] = vz.x; whz[q*4+1] = vz.y; whz[q*4+2] = vz.z; whz[q*4+3] = vz.w;
        whn[q*4+0] = vn.x; whn[q*4+1] = vn.y; whn[q*4+2] = vn.z; whn[q*4+3] = vn.w;
    }
    // fused input weights: 4 of the 8 input channels per lane
    const float4 wxr = *(const float4*)&Wf[(0 * Hn + j) * In + grp * 4];
    const float4 wxz = *(const float4*)&Wf[(1 * Hn + j) * In + grp * 4];
    const float4 wxn = *(const float4*)&Wf[(2 * Hn + j) * In + grp * 4];

    const float br  = b_ih[j]          + b_hh[j];
    const float bz  = b_ih[Hn + j]     + b_hh[Hn + j];
    const float bxn = b_ih[2 * Hn + j];
    const float bhn = b_hh[2 * Hn + j];

    float hj = 0.f;        // h[j] (tracked identically by both halves)
    float h16[16];         // h[k] for k in [grp*16, grp*16+16)
#pragma unroll
    for (int q = 0; q < 16; ++q) h16[q] = 0.f;

    for (int t0 = 0; t0 < Tn; t0 += CH) {
        // stage this chunk's inputs: CH*8 floats = 512 float4
#pragma unroll
        for (int c = 0; c < 8; ++c) {
            int f4 = c * 64 + lane;
            float4 v = *(const float4*)&xb[(size_t)t0 * In + (size_t)f4 * 4];
            *(float4*)&lds_x[f4 * 4] = v;
        }
        __syncthreads();

#pragma unroll 1
        for (int s = 0; s < CH; ++s) {
            // input slice for this lane's K-half
            float4 xv = *(const float4*)&lds_x[s * In + grp * 4];

            float ar0 = 0.f, ar1 = 0.f, az0 = 0.f, az1 = 0.f, an0 = 0.f, an1 = 0.f;
#pragma unroll
            for (int q = 0; q < 8; ++q) {
                ar0 = fmaf(h16[2*q],   whr[2*q],   ar0);
                ar1 = fmaf(h16[2*q+1], whr[2*q+1], ar1);
                az0 = fmaf(h16[2*q],   whz[2*q],   az0);
                az1 = fmaf(h16[2*q+1], whz[2*q+1], az1);
                an0 = fmaf(h16[2*q],   whn[2*q],   an0);
                an1 = fmaf(h16[2*q+1], whn[2*q+1], an1);
            }
            float ar   = ar0 + ar1;
            float az   = az0 + az1;
            float aghn = an0 + an1;   // h-part of n gate (gets b_hh, scaled by r)
            // input-gate contributions (r,z fold into same sum; n kept separate)
            ar = fmaf(xv.x, wxr.x, ar); ar = fmaf(xv.y, wxr.y, ar);
            ar = fmaf(xv.z, wxr.z, ar); ar = fmaf(xv.w, wxr.w, ar);
            az = fmaf(xv.x, wxz.x, az); az = fmaf(xv.y, wxz.y, az);
            az = fmaf(xv.z, wxz.z, az); az = fmaf(xv.w, wxz.w, az);
            float agxn = xv.x * wxn.x;
            agxn = fmaf(xv.y, wxn.y, agxn);
            agxn = fmaf(xv.z, wxn.z, agxn);
            agxn = fmaf(xv.w, wxn.w, agxn);

            // combine the two K-halves
            ar   += __shfl_xor(ar, 32);
            az   += __shfl_xor(az, 32);
            aghn += __shfl_xor(aghn, 32);
            agxn += __shfl_xor(agxn, 32);

            float r = sigm(ar + br);
            float z = sigm(az + bz);
            float n = tanhfast(agxn + bxn + r * (aghn + bhn));
            hj = n + z * (hj - n);

            __syncthreads();            // WAR: previous reads of lds_h done
            if (grp == 0) {
                lds_h[j] = hj;
                lds_lat[s * Hn + j] = hj;
            }
            __syncthreads();            // RAW: h visible to all lanes
#pragma unroll
            for (int q = 0; q < 4; ++q) {
                float4 hv = *(const float4*)&lds_h[grp * 16 + q * 4];
                h16[q*4+0] = hv.x; h16[q*4+1] = hv.y;
                h16[q*4+2] = hv.z; h16[q*4+3] = hv.w;
            }
        }
        __syncthreads();
        // coalesced writeback of this chunk's latents: CH*32 floats = 2048 float4
#pragma unroll
        for (int c = 0; c < 32; ++c) {
            int f4 = c * 64 + lane;
            float4 v = *(const float4*)&lds_lat[f4 * 4];
            *(float4*)&latb[(size_t)t0 * Hn + (size_t)f4 * 4] = v;
        }
    }
}

// outputs[b,t,o] = sum_h latents[b,t,h] * E[h,o]   (TGT==I==8, so E copies whole)
__global__ void decode_kernel(const float* __restrict__ lat,
                              const float* __restrict__ E,
                              float* __restrict__ out) {
    __shared__ float ldsE[Hn * TGTn];
    int tid = threadIdx.x;
    if (tid < Hn * TGTn) ldsE[tid] = E[tid];
    __syncthreads();
    size_t idx = (size_t)blockIdx.x * 256 + tid;   // over B*T*8
    int o      = (int)(idx & (TGTn - 1));
    size_t row = idx >> 3;
    const float* lrow = lat + row * Hn;
    float acc = 0.f;
#pragma unroll
    for (int h = 0; h < Hn; ++h)
        acc = fmaf(lrow[h], ldsE[h * TGTn + o], acc);
    out[idx] = acc;
}

extern "C" void kernel_launch(void* const* d_in, const int* in_sizes, int n_in,
                              void* d_out, int out_size, void* d_ws, size_t ws_size,
                              hipStream_t stream) {
    const float* x    = (const float*)d_in[0];
    const float* E    = (const float*)d_in[1];
    const float* w_ih = (const float*)d_in[2];
    const float* w_hh = (const float*)d_in[3];
    const float* b_ih = (const float*)d_in[4];
    const float* b_hh = (const float*)d_in[5];

    float* out = (float*)d_out;                          // [B,T,8]
    float* lat = out + (size_t)Bsz * Tn * TGTn;          // [B,T,32]
    float* Wf  = (float*)d_ws;                           // [96,8]

    fuse_wih_kernel<<<1, 768, 0, stream>>>(w_ih, E, Wf);
    gru_kernel<<<Bsz, 64, 0, stream>>>(x, Wf, w_hh, b_ih, b_hh, lat);
    decode_kernel<<<(Bsz * Tn * TGTn) / 256, 256, 0, stream>>>(lat, E, out);
}

// Round 5
// 1003.969 us; speedup vs baseline: 1.1513x; 1.1513x over previous
//
#include <hip/hip_runtime.h>
#include <hip/hip_bf16.h>
#include <cstdint>
#include <cstddef>

#define Bsz  256
#define Tn   4096
#define In   8
#define Hn   32
#define TGTn 8

typedef float v2f __attribute__((ext_vector_type(2)));

// packed fp32 fma; lowers to v_pk_fma_f32 when profitable, 2x v_fma_f32 otherwise.
__device__ __forceinline__ v2f pk_fma(v2f a, v2f b, v2f c) {
    return __builtin_elementwise_fma(a, b, c);
}

// DPP rotate within 16-lane rows (0x121..0x12F = ROW_ROR:N); direction probed.
template<int N>
__device__ __forceinline__ float dpp_ror(float x) {
    int xi = __float_as_int(x);
    int r = __builtin_amdgcn_update_dpp(xi, xi, 0x120 + N, 0xF, 0xF, false);
    return __int_as_float(r);
}

// x_l + x_{l^32} in every lane. Builtin returns BOTH swap results; compiler
// materializes the operand copy and the permlane hazard nops (the round-2/3
// inline-asm versions violated the VALU-write -> permlane-read hazard).
__device__ __forceinline__ float half_sum(float x) {
    auto r = __builtin_amdgcn_permlane32_swap(__float_as_int(x), __float_as_int(x),
                                              false, false);
    return __int_as_float((int)r[0]) + __int_as_float((int)r[1]);
}

// From x = f(lane&31) (duplicated across 32-halves) produce the unordered pair
// {f(lane&15), f(16+(lane&15))}; caller probes which slot is which.
__device__ __forceinline__ void row16_pair(float x, float& a_out, float& b_out) {
    auto r = __builtin_amdgcn_permlane16_swap(__float_as_int(x), __float_as_int(x),
                                              false, false);
    a_out = __int_as_float((int)r[0]);
    b_out = __int_as_float((int)r[1]);
}

// 16-lane-row all-gather butterfly: every lane ends with all 16 row values in
// H[0..7] pairs, in a lane-dependent but fixed order (probed at init).
__device__ __forceinline__ void gather16(float v, v2f H[8]) {
    v2f G0; G0.x = v;                G0.y = dpp_ror<1>(v);
    v2f G1; G1.x = dpp_ror<2>(G0.x); G1.y = dpp_ror<2>(G0.y);
    v2f G2; G2.x = dpp_ror<4>(G0.x); G2.y = dpp_ror<4>(G0.y);
    v2f G3; G3.x = dpp_ror<4>(G1.x); G3.y = dpp_ror<4>(G1.y);
    v2f G4; G4.x = dpp_ror<8>(G0.x); G4.y = dpp_ror<8>(G0.y);
    v2f G5; G5.x = dpp_ror<8>(G1.x); G5.y = dpp_ror<8>(G1.y);
    v2f G6; G6.x = dpp_ror<8>(G2.x); G6.y = dpp_ror<8>(G2.y);
    v2f G7; G7.x = dpp_ror<8>(G3.x); G7.y = dpp_ror<8>(G3.y);
    H[0]=G0; H[1]=G1; H[2]=G2; H[3]=G3; H[4]=G4; H[5]=G5; H[6]=G6; H[7]=G7;
}

__device__ __forceinline__ float rcpf(float x) { return __builtin_amdgcn_rcpf(x); }
__device__ __forceinline__ float sigm(float x) { return rcpf(1.f + __expf(-x)); }
__device__ __forceinline__ float tanhfast(float x) {
    float e = __expf(2.f * x);
    return 1.f - 2.f * rcpf(e + 1.f);
}

// W = w_ih @ E : [96,8]
__global__ void fuse_wih_kernel(const float* __restrict__ w_ih,
                                const float* __restrict__ E,
                                float* __restrict__ Wf) {
    int tid = threadIdx.x;                // 768 threads
    int g = tid >> 3, i = tid & 7;
    float acc = 0.f;
#pragma unroll
    for (int k = 0; k < Hn; ++k)
        acc = fmaf(w_ih[g * Hn + k], E[k * In + i], acc);
    Wf[g * In + i] = acc;
}

// One block = one batch element, ONE wave. No LDS, no barriers, no inline asm:
// cross-lane traffic is permlane-swap builtins + DPP butterfly, weights
// pre-permuted at init to match the probed lane order.
__launch_bounds__(64, 1)
__global__ void gru_kernel(const float* __restrict__ x,     // [B,T,8]
                           const float* __restrict__ Wf,    // [96,8] fused w_ih@E
                           const float* __restrict__ w_hh,  // [96,32]
                           const float* __restrict__ b_ih,  // [96]
                           const float* __restrict__ b_hh,  // [96]
                           float* __restrict__ latents) {   // [B,T,32]
    const int lane = threadIdx.x & 63;
    const int grp  = lane >> 5;     // K/I half this lane accumulates
    const int j    = lane & 31;     // hidden row this lane produces
    const int r16  = lane & 15;
    const int b    = blockIdx.x;

    // ---- self-calibration: probe the hardware's permutation conventions ----
    int sidx[16];
    {
        v2f P[8];
        gather16((float)r16, P);
#pragma unroll
        for (int q = 0; q < 8; ++q) {
            sidx[2*q]   = (int)P[q].x;
            sidx[2*q+1] = (int)P[q].y;
        }
    }
    bool pick_a;
    {
        float va, vb;
        row16_pair((float)j, va, vb);
        pick_a = ((int)va == grp * 16 + r16);
    }

    // ---- weights, permuted so gathered-h register order matches ----
    v2f whr[8], whz[8], whn[8];
#pragma unroll
    for (int q = 0; q < 8; ++q) {
        const int c0 = grp * 16 + sidx[2*q], c1 = grp * 16 + sidx[2*q+1];
        whr[q] = v2f{w_hh[(0*Hn + j)*Hn + c0], w_hh[(0*Hn + j)*Hn + c1]};
        whz[q] = v2f{w_hh[(1*Hn + j)*Hn + c0], w_hh[(1*Hn + j)*Hn + c1]};
        whn[q] = v2f{w_hh[(2*Hn + j)*Hn + c0], w_hh[(2*Hn + j)*Hn + c1]};
    }
    v2f wxr[2], wxz[2], wxn[2];
#pragma unroll
    for (int q = 0; q < 2; ++q) {
        wxr[q] = v2f{Wf[(0*Hn+j)*In + grp*4 + 2*q], Wf[(0*Hn+j)*In + grp*4 + 2*q + 1]};
        wxz[q] = v2f{Wf[(1*Hn+j)*In + grp*4 + 2*q], Wf[(1*Hn+j)*In + grp*4 + 2*q + 1]};
        wxn[q] = v2f{Wf[(2*Hn+j)*In + grp*4 + 2*q], Wf[(2*Hn+j)*In + grp*4 + 2*q + 1]};
    }
    // half-biases: each K-half carries 0.5*b; the permlane half-sum restores b
    const float brh  = 0.5f * (b_ih[j]        + b_hh[j]);
    const float bzh  = 0.5f * (b_ih[Hn + j]   + b_hh[Hn + j]);
    const float bxnh = 0.5f * b_ih[2*Hn + j];
    const float bhnh = 0.5f * b_hh[2*Hn + j];

    const float* xb = x + (size_t)b * Tn * In;
    float* latb     = latents + (size_t)b * Tn * Hn;

    float hj = 0.f;
    v2f H[8];
#pragma unroll
    for (int q = 0; q < 8; ++q) H[q] = v2f{0.f, 0.f};

    // ---- 8-deep x prefetch ring (wrap-masked: tail loads stay in-bounds) ----
    float4 xring[8];
#pragma unroll
    for (int u = 0; u < 8; ++u)
        xring[u] = *(const float4*)&xb[(size_t)u * In + grp * 4];

    float axr, axz, cxn;
    {   // pre-activations for step 0
        float4 xq = xring[0];
        v2f x0 = v2f{xq.x, xq.y}, x1 = v2f{xq.z, xq.w};
        v2f zr = v2f{0.f, 0.f};
        v2f a  = pk_fma(x0, wxr[0], pk_fma(x1, wxr[1], zr));
        axr = a.x + a.y + brh;
        v2f bb = pk_fma(x0, wxz[0], pk_fma(x1, wxz[1], zr));
        axz = bb.x + bb.y + bzh;
        v2f cc = pk_fma(x0, wxn[0], pk_fma(x1, wxn[1], zr));
        cxn = half_sum(cc.x + cc.y + bxnh);
    }

#pragma unroll 1
    for (int s0 = 0; s0 < Tn; s0 += 8) {
#pragma unroll
        for (int u = 0; u < 8; ++u) {
            const int s = s0 + u;

            // ---- recurrent dots over this lane's K-half ----
            v2f ar = v2f{0.f, 0.f}, az = v2f{0.f, 0.f}, an = v2f{0.f, 0.f};
#pragma unroll
            for (int q = 0; q < 8; ++q) {
                ar = pk_fma(H[q], whr[q], ar);
                az = pk_fma(H[q], whz[q], az);
                an = pk_fma(H[q], whn[q], an);
            }
            float pr  = ar.x + ar.y + axr;
            float pz  = az.x + az.y + axz;
            float phn = an.x + an.y + bhnh;

            float cr  = half_sum(pr);
            float cz  = half_sum(pz);
            float chn = half_sum(phn);

            float r = sigm(cr);
            float z = sigm(cz);
            float n = tanhfast(cxn + r * chn);
            hj = n + z * (hj - n);

            // ---- VALU-only h broadcast ----
            float va, vb;
            row16_pair(hj, va, vb);
            float v = pick_a ? va : vb;     // = h[grp*16 + (lane&15)]
            gather16(v, H);

            // ---- shadow work (off the h critical path) ----
            latb[(size_t)s * Hn + j] = hj;

            {   // pre-activations for step s+1 (x[s+1] lives in xring[(u+1)&7])
                float4 xq = xring[(u + 1) & 7];
                v2f x0 = v2f{xq.x, xq.y}, x1 = v2f{xq.z, xq.w};
                v2f zr = v2f{0.f, 0.f};
                v2f a  = pk_fma(x0, wxr[0], pk_fma(x1, wxr[1], zr));
                axr = a.x + a.y + brh;
                v2f bb = pk_fma(x0, wxz[0], pk_fma(x1, wxz[1], zr));
                axz = bb.x + bb.y + bzh;
                v2f cc = pk_fma(x0, wxn[0], pk_fma(x1, wxn[1], zr));
                cxn = half_sum(cc.x + cc.y + bxnh);
            }
            // refill ring 8 steps ahead (mask keeps the tail in-bounds; the
            // wrapped values are never consumed)
            const int sn = (s + 8) & (Tn - 1);
            xring[u] = *(const float4*)&xb[(size_t)sn * In + grp * 4];
        }
    }
}

// outputs[b,t,o] = sum_h latents[b,t,h] * E[h,o]
__global__ void decode_kernel(const float* __restrict__ lat,
                              const float* __restrict__ E,
                              float* __restrict__ out) {
    __shared__ float ldsE[Hn * TGTn];
    int tid = threadIdx.x;
    if (tid < Hn * TGTn) ldsE[tid] = E[tid];
    __syncthreads();
    size_t idx = (size_t)blockIdx.x * 256 + tid;   // over B*T*8
    int o      = (int)(idx & (TGTn - 1));
    size_t row = idx >> 3;
    const float* lrow = lat + row * Hn;
    float acc = 0.f;
#pragma unroll
    for (int h = 0; h < Hn; ++h)
        acc = fmaf(lrow[h], ldsE[h * TGTn + o], acc);
    out[idx] = acc;
}

extern "C" void kernel_launch(void* const* d_in, const int* in_sizes, int n_in,
                              void* d_out, int out_size, void* d_ws, size_t ws_size,
                              hipStream_t stream) {
    const float* x    = (const float*)d_in[0];
    const float* E    = (const float*)d_in[1];
    const float* w_ih = (const float*)d_in[2];
    const float* w_hh = (const float*)d_in[3];
    const float* b_ih = (const float*)d_in[4];
    const float* b_hh = (const float*)d_in[5];

    float* out = (float*)d_out;                          // [B,T,8]
    float* lat = out + (size_t)Bsz * Tn * TGTn;          // [B,T,32]
    float* Wf  = (float*)d_ws;                           // [96,8]

    fuse_wih_kernel<<<1, 768, 0, stream>>>(w_ih, E, Wf);
    gru_kernel<<<Bsz, 64, 0, stream>>>(x, Wf, w_hh, b_ih, b_hh, lat);
    decode_kernel<<<(Bsz * Tn * TGTn) / 256, 256, 0, stream>>>(lat, E, out);
}

// Round 6
// 993.636 us; speedup vs baseline: 1.1632x; 1.0104x over previous
//
#include <hip/hip_runtime.h>
#include <hip/hip_bf16.h>
#include <cstdint>
#include <cstddef>

#define Bsz  256
#define Tn   4096
#define In   8
#define Hn   32
#define TGTn 8

typedef float v2f __attribute__((ext_vector_type(2)));

__device__ __forceinline__ v2f pk_fma(v2f a, v2f b, v2f c) {
    return __builtin_elementwise_fma(a, b, c);
}
__device__ __forceinline__ v2f pk_mul(v2f a, v2f b) { return a * b; }

// DPP rotate within 16-lane rows; direction convention handled by probing.
template<int N>
__device__ __forceinline__ float dpp_ror(float x) {
    int xi = __float_as_int(x);
    int r = __builtin_amdgcn_update_dpp(xi, xi, 0x120 + N, 0xF, 0xF, false);
    return __int_as_float(r);
}

// x_l + x_{l^32} in every lane (hazards managed by compiler — builtin, not asm).
__device__ __forceinline__ float half_sum(float x) {
    auto r = __builtin_amdgcn_permlane32_swap(__float_as_int(x), __float_as_int(x),
                                              false, false);
    return __int_as_float((int)r[0]) + __int_as_float((int)r[1]);
}

// Unordered pair {f(lane&15), f(16+(lane&15))}; caller probes slot order.
__device__ __forceinline__ void row16_pair(float x, float& a_out, float& b_out) {
    auto r = __builtin_amdgcn_permlane16_swap(__float_as_int(x), __float_as_int(x),
                                              false, false);
    a_out = __int_as_float((int)r[0]);
    b_out = __int_as_float((int)r[1]);
}

// Array-based butterfly — used ONLY for the init-time probe (cold code).
// Must match the macro's H0..H7 assignments exactly.
__device__ __forceinline__ void gather16_probe(float v, v2f H[8]) {
    v2f G0; G0.x = v;                G0.y = dpp_ror<1>(v);
    v2f G1; G1.x = dpp_ror<2>(G0.x); G1.y = dpp_ror<2>(G0.y);
    v2f G2; G2.x = dpp_ror<4>(G0.x); G2.y = dpp_ror<4>(G0.y);
    v2f G3; G3.x = dpp_ror<4>(G1.x); G3.y = dpp_ror<4>(G1.y);
    v2f G4; G4.x = dpp_ror<8>(G0.x); G4.y = dpp_ror<8>(G0.y);
    v2f G5; G5.x = dpp_ror<8>(G1.x); G5.y = dpp_ror<8>(G1.y);
    v2f G6; G6.x = dpp_ror<8>(G2.x); G6.y = dpp_ror<8>(G2.y);
    v2f G7; G7.x = dpp_ror<8>(G3.x); G7.y = dpp_ror<8>(G3.y);
    H[0]=G0; H[1]=G1; H[2]=G2; H[3]=G3; H[4]=G4; H[5]=G5; H[6]=G6; H[7]=G7;
}

__device__ __forceinline__ float rcpf(float x) { return __builtin_amdgcn_rcpf(x); }
__device__ __forceinline__ float sigm(float x) { return rcpf(1.f + __expf(-x)); }
__device__ __forceinline__ float tanhfast(float x) {
    float e = __expf(2.f * x);
    return 1.f - 2.f * rcpf(e + 1.f);
}

// W = w_ih @ E : [96,8]
__global__ void fuse_wih_kernel(const float* __restrict__ w_ih,
                                const float* __restrict__ E,
                                float* __restrict__ Wf) {
    int tid = threadIdx.x;                // 768 threads
    int g = tid >> 3, i = tid & 7;
    float acc = 0.f;
#pragma unroll
    for (int k = 0; k < Hn; ++k)
        acc = fmaf(w_ih[g * Hn + k], E[k * In + i], acc);
    Wf[g * In + i] = acc;
}

// One step of the GRU. All operands are NAMED registers (no arrays -> no
// scratch demotion, rule #20). XNEXT = ring slot holding x[s+1] (feeds next
// step's pre-activations); XREFILL = ring slot freed this step (gets x[s+8]).
#define GRU_STEP(XNEXT, XREFILL, DO_REFILL)                                          \
  {                                                                                  \
    v2f ar0 = pk_fma(H0, whr0, pk_fma(H2, whr2, pk_fma(H4, whr4, pk_mul(H6, whr6))));\
    v2f ar1 = pk_fma(H1, whr1, pk_fma(H3, whr3, pk_fma(H5, whr5, pk_mul(H7, whr7))));\
    v2f az0 = pk_fma(H0, whz0, pk_fma(H2, whz2, pk_fma(H4, whz4, pk_mul(H6, whz6))));\
    v2f az1 = pk_fma(H1, whz1, pk_fma(H3, whz3, pk_fma(H5, whz5, pk_mul(H7, whz7))));\
    v2f an0 = pk_fma(H0, whn0, pk_fma(H2, whn2, pk_fma(H4, whn4, pk_mul(H6, whn6))));\
    v2f an1 = pk_fma(H1, whn1, pk_fma(H3, whn3, pk_fma(H5, whn5, pk_mul(H7, whn7))));\
    v2f art = ar0 + ar1;                                                             \
    v2f azt = az0 + az1;                                                             \
    v2f ant = an0 + an1;                                                             \
    float pr  = art.x + art.y + axr;                                                 \
    float pz  = azt.x + azt.y + axz;                                                 \
    float phn = ant.x + ant.y + bhnh;                                                \
    float cr  = half_sum(pr);                                                        \
    float cz  = half_sum(pz);                                                        \
    float chn = half_sum(phn);                                                       \
    float r = sigm(cr);                                                              \
    float z = sigm(cz);                                                              \
    float n = tanhfast(cxn + r * chn);                                               \
    hj = __builtin_fmaf(z, hj - n, n);                                               \
    float va, vb;                                                                    \
    row16_pair(hj, va, vb);                                                          \
    float gv = pick_a ? va : vb;          /* = h[grp*16 + (lane&15)] */              \
    H0 = v2f{gv, dpp_ror<1>(gv)};                                                    \
    H1 = v2f{dpp_ror<2>(H0.x), dpp_ror<2>(H0.y)};                                    \
    H2 = v2f{dpp_ror<4>(H0.x), dpp_ror<4>(H0.y)};                                    \
    H3 = v2f{dpp_ror<4>(H1.x), dpp_ror<4>(H1.y)};                                    \
    H4 = v2f{dpp_ror<8>(H0.x), dpp_ror<8>(H0.y)};                                    \
    H5 = v2f{dpp_ror<8>(H1.x), dpp_ror<8>(H1.y)};                                    \
    H6 = v2f{dpp_ror<8>(H2.x), dpp_ror<8>(H2.y)};                                    \
    H7 = v2f{dpp_ror<8>(H3.x), dpp_ror<8>(H3.y)};                                    \
    *latp = hj;                                                                      \
    latp += Hn;                                                                      \
    {                                                                                \
      v2f nx0 = v2f{XNEXT.x, XNEXT.y}, nx1 = v2f{XNEXT.z, XNEXT.w};                  \
      v2f ta = pk_fma(nx0, wxr0, pk_mul(nx1, wxr1));                                 \
      axr = ta.x + ta.y + brh;                                                       \
      v2f tb = pk_fma(nx0, wxz0, pk_mul(nx1, wxz1));                                 \
      axz = tb.x + tb.y + bzh;                                                       \
      v2f tc = pk_fma(nx0, wxn0, pk_mul(nx1, wxn1));                                 \
      cxn = half_sum(tc.x + tc.y + bxnh);                                            \
    }                                                                                \
    if (DO_REFILL) { XREFILL = *(const float4*)refp; refp += In; }                   \
  }

// One block = one batch element, ONE wave. No LDS, no barriers, no inline asm,
// and (this round) no arrays in the hot loop — everything is named registers.
__launch_bounds__(64, 1)
__global__ void gru_kernel(const float* __restrict__ x,     // [B,T,8]
                           const float* __restrict__ Wf,    // [96,8] fused w_ih@E
                           const float* __restrict__ w_hh,  // [96,32]
                           const float* __restrict__ b_ih,  // [96]
                           const float* __restrict__ b_hh,  // [96]
                           float* __restrict__ latents) {   // [B,T,32]
    const int lane = threadIdx.x & 63;
    const int grp  = lane >> 5;     // K/I half this lane accumulates
    const int j    = lane & 31;     // hidden row this lane produces
    const int r16  = lane & 15;
    const int b    = blockIdx.x;

    // ---- self-calibration: probe the hardware's permutation conventions ----
    int sidx[16];
    {
        v2f P[8];
        gather16_probe((float)r16, P);
#pragma unroll
        for (int q = 0; q < 8; ++q) {
            sidx[2*q]   = (int)P[q].x;
            sidx[2*q+1] = (int)P[q].y;
        }
    }
    bool pick_a;
    {
        float va, vb;
        row16_pair((float)j, va, vb);
        pick_a = ((int)va == grp * 16 + r16);
    }

    // ---- weights into NAMED registers, permuted to the probed lane order ----
    v2f whr0, whr1, whr2, whr3, whr4, whr5, whr6, whr7;
    v2f whz0, whz1, whz2, whz3, whz4, whz5, whz6, whz7;
    v2f whn0, whn1, whn2, whn3, whn4, whn5, whn6, whn7;
#define LOADW(Q)                                                                  \
    {                                                                             \
        const int c0 = grp * 16 + sidx[2*Q], c1 = grp * 16 + sidx[2*Q+1];         \
        whr##Q = v2f{w_hh[(0*Hn + j)*Hn + c0], w_hh[(0*Hn + j)*Hn + c1]};         \
        whz##Q = v2f{w_hh[(1*Hn + j)*Hn + c0], w_hh[(1*Hn + j)*Hn + c1]};         \
        whn##Q = v2f{w_hh[(2*Hn + j)*Hn + c0], w_hh[(2*Hn + j)*Hn + c1]};         \
    }
    LOADW(0) LOADW(1) LOADW(2) LOADW(3) LOADW(4) LOADW(5) LOADW(6) LOADW(7)
#undef LOADW

    const v2f wxr0 = v2f{Wf[(0*Hn+j)*In + grp*4 + 0], Wf[(0*Hn+j)*In + grp*4 + 1]};
    const v2f wxr1 = v2f{Wf[(0*Hn+j)*In + grp*4 + 2], Wf[(0*Hn+j)*In + grp*4 + 3]};
    const v2f wxz0 = v2f{Wf[(1*Hn+j)*In + grp*4 + 0], Wf[(1*Hn+j)*In + grp*4 + 1]};
    const v2f wxz1 = v2f{Wf[(1*Hn+j)*In + grp*4 + 2], Wf[(1*Hn+j)*In + grp*4 + 3]};
    const v2f wxn0 = v2f{Wf[(2*Hn+j)*In + grp*4 + 0], Wf[(2*Hn+j)*In + grp*4 + 1]};
    const v2f wxn1 = v2f{Wf[(2*Hn+j)*In + grp*4 + 2], Wf[(2*Hn+j)*In + grp*4 + 3]};

    // half-biases: each K-half carries 0.5*b; the permlane half-sum restores b
    const float brh  = 0.5f * (b_ih[j]        + b_hh[j]);
    const float bzh  = 0.5f * (b_ih[Hn + j]   + b_hh[Hn + j]);
    const float bxnh = 0.5f * b_ih[2*Hn + j];
    const float bhnh = 0.5f * b_hh[2*Hn + j];

    const float* xb = x + (size_t)b * Tn * In;
    float* latp     = latents + (size_t)b * Tn * Hn + j;   // advances Hn/step
    const float* refp = xb + (size_t)8 * In + grp * 4;     // next refill = x[8]

    float hj = 0.f;
    v2f H0{0.f,0.f}, H1{0.f,0.f}, H2{0.f,0.f}, H3{0.f,0.f},
        H4{0.f,0.f}, H5{0.f,0.f}, H6{0.f,0.f}, H7{0.f,0.f};

    // ---- 8-deep x ring in NAMED float4 slots ----
    float4 x0 = *(const float4*)&xb[0*In + grp*4];
    float4 x1 = *(const float4*)&xb[1*In + grp*4];
    float4 x2 = *(const float4*)&xb[2*In + grp*4];
    float4 x3 = *(const float4*)&xb[3*In + grp*4];
    float4 x4 = *(const float4*)&xb[4*In + grp*4];
    float4 x5 = *(const float4*)&xb[5*In + grp*4];
    float4 x6 = *(const float4*)&xb[6*In + grp*4];
    float4 x7 = *(const float4*)&xb[7*In + grp*4];

    float axr, axz, cxn;
    {   // pre-activations for step 0 (from slot x0)
        v2f nx0 = v2f{x0.x, x0.y}, nx1 = v2f{x0.z, x0.w};
        v2f ta = pk_fma(nx0, wxr0, pk_mul(nx1, wxr1));
        axr = ta.x + ta.y + brh;
        v2f tb = pk_fma(nx0, wxz0, pk_mul(nx1, wxz1));
        axz = tb.x + tb.y + bzh;
        v2f tc = pk_fma(nx0, wxn0, pk_mul(nx1, wxn1));
        cxn = half_sum(tc.x + tc.y + bxnh);
    }

    // main loop: steps 0..4087 (511 groups of 8), refilling x[s+8] each step
#pragma unroll 1
    for (int s0 = 0; s0 < Tn - 8; s0 += 8) {
        GRU_STEP(x1, x0, true)
        GRU_STEP(x2, x1, true)
        GRU_STEP(x3, x2, true)
        GRU_STEP(x4, x3, true)
        GRU_STEP(x5, x4, true)
        GRU_STEP(x6, x5, true)
        GRU_STEP(x7, x6, true)
        GRU_STEP(x0, x7, true)
    }
    // epilogue: steps 4088..4095, no refills (slots hold x[4088..4095])
    GRU_STEP(x1, x0, false)
    GRU_STEP(x2, x1, false)
    GRU_STEP(x3, x2, false)
    GRU_STEP(x4, x3, false)
    GRU_STEP(x5, x4, false)
    GRU_STEP(x6, x5, false)
    GRU_STEP(x7, x6, false)
    GRU_STEP(x0, x7, false)
}

// outputs[b,t,o] = sum_h latents[b,t,h] * E[h,o]
__global__ void decode_kernel(const float* __restrict__ lat,
                              const float* __restrict__ E,
                              float* __restrict__ out) {
    __shared__ float ldsE[Hn * TGTn];
    int tid = threadIdx.x;
    if (tid < Hn * TGTn) ldsE[tid] = E[tid];
    __syncthreads();
    size_t idx = (size_t)blockIdx.x * 256 + tid;   // over B*T*8
    int o      = (int)(idx & (TGTn - 1));
    size_t row = idx >> 3;
    const float* lrow = lat + row * Hn;
    float acc = 0.f;
#pragma unroll
    for (int h = 0; h < Hn; ++h)
        acc = fmaf(lrow[h], ldsE[h * TGTn + o], acc);
    out[idx] = acc;
}

extern "C" void kernel_launch(void* const* d_in, const int* in_sizes, int n_in,
                              void* d_out, int out_size, void* d_ws, size_t ws_size,
                              hipStream_t stream) {
    const float* x    = (const float*)d_in[0];
    const float* E    = (const float*)d_in[1];
    const float* w_ih = (const float*)d_in[2];
    const float* w_hh = (const float*)d_in[3];
    const float* b_ih = (const float*)d_in[4];
    const float* b_hh = (const float*)d_in[5];

    float* out = (float*)d_out;                          // [B,T,8]
    float* lat = out + (size_t)Bsz * Tn * TGTn;          // [B,T,32]
    float* Wf  = (float*)d_ws;                           // [96,8]

    fuse_wih_kernel<<<1, 768, 0, stream>>>(w_ih, E, Wf);
    gru_kernel<<<Bsz, 64, 0, stream>>>(x, Wf, w_hh, b_ih, b_hh, lat);
    decode_kernel<<<(Bsz * Tn * TGTn) / 256, 256, 0, stream>>>(lat, E, out);
}

// Round 7
// 992.461 us; speedup vs baseline: 1.1646x; 1.0012x over previous
//
#include <hip/hip_runtime.h>
#include <hip/hip_bf16.h>
#include <cstdint>
#include <cstddef>

#define Bsz  256
#define Tn   4096
#define In   8
#define Hn   32
#define TGTn 8

typedef float v2f __attribute__((ext_vector_type(2)));

__device__ __forceinline__ v2f pk_fma(v2f a, v2f b, v2f c) {
    return __builtin_elementwise_fma(a, b, c);
}
__device__ __forceinline__ v2f pk_mul(v2f a, v2f b) { return a * b; }

// DPP rotate within 16-lane rows; direction convention handled by probing.
template<int N>
__device__ __forceinline__ float dpp_ror(float x) {
    int xi = __float_as_int(x);
    int r = __builtin_amdgcn_update_dpp(xi, xi, 0x120 + N, 0xF, 0xF, false);
    return __int_as_float(r);
}

// x_l + x_{l^32} in every lane (hazards managed by compiler — builtin, not asm).
__device__ __forceinline__ float half_sum(float x) {
    auto r = __builtin_amdgcn_permlane32_swap(__float_as_int(x), __float_as_int(x),
                                              false, false);
    return __int_as_float((int)r[0]) + __int_as_float((int)r[1]);
}

// Unordered pair {f(lane&15), f(16+(lane&15))}; caller probes slot order.
__device__ __forceinline__ void row16_pair(float x, float& a_out, float& b_out) {
    auto r = __builtin_amdgcn_permlane16_swap(__float_as_int(x), __float_as_int(x),
                                              false, false);
    a_out = __int_as_float((int)r[0]);
    b_out = __int_as_float((int)r[1]);
}

// Array-based butterfly — used ONLY for the init-time probe (cold code).
// Must match the macro's H0..H7 assignments exactly.
__device__ __forceinline__ void gather16_probe(float v, v2f H[8]) {
    v2f G0; G0.x = v;                G0.y = dpp_ror<1>(v);
    v2f G1; G1.x = dpp_ror<2>(G0.x); G1.y = dpp_ror<2>(G0.y);
    v2f G2; G2.x = dpp_ror<4>(G0.x); G2.y = dpp_ror<4>(G0.y);
    v2f G3; G3.x = dpp_ror<4>(G1.x); G3.y = dpp_ror<4>(G1.y);
    v2f G4; G4.x = dpp_ror<8>(G0.x); G4.y = dpp_ror<8>(G0.y);
    v2f G5; G5.x = dpp_ror<8>(G1.x); G5.y = dpp_ror<8>(G1.y);
    v2f G6; G6.x = dpp_ror<8>(G2.x); G6.y = dpp_ror<8>(G2.y);
    v2f G7; G7.x = dpp_ror<8>(G3.x); G7.y = dpp_ror<8>(G3.y);
    H[0]=G0; H[1]=G1; H[2]=G2; H[3]=G3; H[4]=G4; H[5]=G5; H[6]=G6; H[7]=G7;
}

__device__ __forceinline__ float rcpf(float x) { return __builtin_amdgcn_rcpf(x); }
__device__ __forceinline__ float sigm(float x) { return rcpf(1.f + __expf(-x)); }
__device__ __forceinline__ float tanhfast(float x) {
    float e = __expf(2.f * x);
    return 1.f - 2.f * rcpf(e + 1.f);
}

// W = w_ih @ E : [96,8]
__global__ void fuse_wih_kernel(const float* __restrict__ w_ih,
                                const float* __restrict__ E,
                                float* __restrict__ Wf) {
    int tid = threadIdx.x;                // 768 threads
    int g = tid >> 3, i = tid & 7;
    float acc = 0.f;
#pragma unroll
    for (int k = 0; k < Hn; ++k)
        acc = fmaf(w_ih[g * Hn + k], E[k * In + i], acc);
    Wf[g * In + i] = acc;
}

// One step of the GRU. All operands are NAMED registers. XNEXT = ring slot
// holding x[s+1] (feeds next step's pre-activations); XREFILL = slot freed
// this step (gets x[s+8]).
#define GRU_STEP(XNEXT, XREFILL, DO_REFILL)                                          \
  {                                                                                  \
    v2f ar0 = pk_fma(H0, whr0, pk_fma(H2, whr2, pk_fma(H4, whr4, pk_mul(H6, whr6))));\
    v2f ar1 = pk_fma(H1, whr1, pk_fma(H3, whr3, pk_fma(H5, whr5, pk_mul(H7, whr7))));\
    v2f az0 = pk_fma(H0, whz0, pk_fma(H2, whz2, pk_fma(H4, whz4, pk_mul(H6, whz6))));\
    v2f az1 = pk_fma(H1, whz1, pk_fma(H3, whz3, pk_fma(H5, whz5, pk_mul(H7, whz7))));\
    v2f an0 = pk_fma(H0, whn0, pk_fma(H2, whn2, pk_fma(H4, whn4, pk_mul(H6, whn6))));\
    v2f an1 = pk_fma(H1, whn1, pk_fma(H3, whn3, pk_fma(H5, whn5, pk_mul(H7, whn7))));\
    v2f art = ar0 + ar1;                                                             \
    v2f azt = az0 + az1;                                                             \
    v2f ant = an0 + an1;                                                             \
    float pr  = art.x + art.y + axr;                                                 \
    float pz  = azt.x + azt.y + axz;                                                 \
    float phn = ant.x + ant.y + bhnh;                                                \
    float cr  = half_sum(pr);                                                        \
    float cz  = half_sum(pz);                                                        \
    float chn = half_sum(phn);                                                       \
    float r = sigm(cr);                                                              \
    float z = sigm(cz);                                                              \
    float n = tanhfast(cxn + r * chn);                                               \
    hj = __builtin_fmaf(z, hj - n, n);                                               \
    float va, vb;                                                                    \
    row16_pair(hj, va, vb);                                                          \
    float gv = pick_a ? va : vb;          /* = h[grp*16 + (lane&15)] */              \
    H0 = v2f{gv, dpp_ror<1>(gv)};                                                    \
    H1 = v2f{dpp_ror<2>(H0.x), dpp_ror<2>(H0.y)};                                    \
    H2 = v2f{dpp_ror<4>(H0.x), dpp_ror<4>(H0.y)};                                    \
    H3 = v2f{dpp_ror<4>(H1.x), dpp_ror<4>(H1.y)};                                    \
    H4 = v2f{dpp_ror<8>(H0.x), dpp_ror<8>(H0.y)};                                    \
    H5 = v2f{dpp_ror<8>(H1.x), dpp_ror<8>(H1.y)};                                    \
    H6 = v2f{dpp_ror<8>(H2.x), dpp_ror<8>(H2.y)};                                    \
    H7 = v2f{dpp_ror<8>(H3.x), dpp_ror<8>(H3.y)};                                    \
    *latp = hj;                                                                      \
    latp += Hn;                                                                      \
    {                                                                                \
      v2f nx0 = v2f{XNEXT.x, XNEXT.y}, nx1 = v2f{XNEXT.z, XNEXT.w};                  \
      v2f ta = pk_fma(nx0, wxr0, pk_mul(nx1, wxr1));                                 \
      axr = ta.x + ta.y + brh;                                                       \
      v2f tb = pk_fma(nx0, wxz0, pk_mul(nx1, wxz1));                                 \
      axz = tb.x + tb.y + bzh;                                                       \
      v2f tc = pk_fma(nx0, wxn0, pk_mul(nx1, wxn1));                                 \
      cxn = half_sum(tc.x + tc.y + bxnh);                                            \
    }                                                                                \
    if (DO_REFILL) { XREFILL = *(const float4*)refp; refp += In; }                   \
  }

// One block = one batch element, ONE wave. waves_per_eu(1,1) lifts the VGPR
// budget to 512 (the default 8-wave occupancy target capped us at 64 VGPRs and
// forced per-step weight reloads). KEEP() pins loop-invariants in registers:
// an asm output cannot be rematerialized from memory.
#define KEEP(v) asm volatile("" : "+v"(v))
__attribute__((amdgpu_flat_work_group_size(64, 64), amdgpu_waves_per_eu(1, 1)))
__global__ void gru_kernel(const float* __restrict__ x,     // [B,T,8]
                           const float* __restrict__ Wf,    // [96,8] fused w_ih@E
                           const float* __restrict__ w_hh,  // [96,32]
                           const float* __restrict__ b_ih,  // [96]
                           const float* __restrict__ b_hh,  // [96]
                           float* __restrict__ latents) {   // [B,T,32]
    const int lane = threadIdx.x & 63;
    const int grp  = lane >> 5;     // K/I half this lane accumulates
    const int j    = lane & 31;     // hidden row this lane produces
    const int r16  = lane & 15;
    const int b    = blockIdx.x;

    // ---- self-calibration: probe the hardware's permutation conventions ----
    int sidx[16];
    {
        v2f P[8];
        gather16_probe((float)r16, P);
#pragma unroll
        for (int q = 0; q < 8; ++q) {
            sidx[2*q]   = (int)P[q].x;
            sidx[2*q+1] = (int)P[q].y;
        }
    }
    bool pick_a;
    {
        float va, vb;
        row16_pair((float)j, va, vb);
        pick_a = ((int)va == grp * 16 + r16);
    }

    // ---- weights into NAMED registers, permuted to the probed lane order ----
    v2f whr0, whr1, whr2, whr3, whr4, whr5, whr6, whr7;
    v2f whz0, whz1, whz2, whz3, whz4, whz5, whz6, whz7;
    v2f whn0, whn1, whn2, whn3, whn4, whn5, whn6, whn7;
#define LOADW(Q)                                                                  \
    {                                                                             \
        const int c0 = grp * 16 + sidx[2*Q], c1 = grp * 16 + sidx[2*Q+1];         \
        whr##Q = v2f{w_hh[(0*Hn + j)*Hn + c0], w_hh[(0*Hn + j)*Hn + c1]};         \
        whz##Q = v2f{w_hh[(1*Hn + j)*Hn + c0], w_hh[(1*Hn + j)*Hn + c1]};         \
        whn##Q = v2f{w_hh[(2*Hn + j)*Hn + c0], w_hh[(2*Hn + j)*Hn + c1]};         \
        KEEP(whr##Q); KEEP(whz##Q); KEEP(whn##Q);                                 \
    }
    LOADW(0) LOADW(1) LOADW(2) LOADW(3) LOADW(4) LOADW(5) LOADW(6) LOADW(7)
#undef LOADW

    v2f wxr0 = v2f{Wf[(0*Hn+j)*In + grp*4 + 0], Wf[(0*Hn+j)*In + grp*4 + 1]};
    v2f wxr1 = v2f{Wf[(0*Hn+j)*In + grp*4 + 2], Wf[(0*Hn+j)*In + grp*4 + 3]};
    v2f wxz0 = v2f{Wf[(1*Hn+j)*In + grp*4 + 0], Wf[(1*Hn+j)*In + grp*4 + 1]};
    v2f wxz1 = v2f{Wf[(1*Hn+j)*In + grp*4 + 2], Wf[(1*Hn+j)*In + grp*4 + 3]};
    v2f wxn0 = v2f{Wf[(2*Hn+j)*In + grp*4 + 0], Wf[(2*Hn+j)*In + grp*4 + 1]};
    v2f wxn1 = v2f{Wf[(2*Hn+j)*In + grp*4 + 2], Wf[(2*Hn+j)*In + grp*4 + 3]};
    KEEP(wxr0); KEEP(wxr1); KEEP(wxz0); KEEP(wxz1); KEEP(wxn0); KEEP(wxn1);

    // half-biases: each K-half carries 0.5*b; the permlane half-sum restores b
    float brh  = 0.5f * (b_ih[j]        + b_hh[j]);
    float bzh  = 0.5f * (b_ih[Hn + j]   + b_hh[Hn + j]);
    float bxnh = 0.5f * b_ih[2*Hn + j];
    float bhnh = 0.5f * b_hh[2*Hn + j];
    KEEP(brh); KEEP(bzh); KEEP(bxnh); KEEP(bhnh);

    const float* xb = x + (size_t)b * Tn * In;
    float* latp     = latents + (size_t)b * Tn * Hn + j;   // advances Hn/step
    const float* refp = xb + (size_t)8 * In + grp * 4;     // next refill = x[8]

    float hj = 0.f;
    v2f H0{0.f,0.f}, H1{0.f,0.f}, H2{0.f,0.f}, H3{0.f,0.f},
        H4{0.f,0.f}, H5{0.f,0.f}, H6{0.f,0.f}, H7{0.f,0.f};

    // ---- 8-deep x ring in NAMED float4 slots ----
    float4 x0 = *(const float4*)&xb[0*In + grp*4];
    float4 x1 = *(const float4*)&xb[1*In + grp*4];
    float4 x2 = *(const float4*)&xb[2*In + grp*4];
    float4 x3 = *(const float4*)&xb[3*In + grp*4];
    float4 x4 = *(const float4*)&xb[4*In + grp*4];
    float4 x5 = *(const float4*)&xb[5*In + grp*4];
    float4 x6 = *(const float4*)&xb[6*In + grp*4];
    float4 x7 = *(const float4*)&xb[7*In + grp*4];

    float axr, axz, cxn;
    {   // pre-activations for step 0 (from slot x0)
        v2f nx0 = v2f{x0.x, x0.y}, nx1 = v2f{x0.z, x0.w};
        v2f ta = pk_fma(nx0, wxr0, pk_mul(nx1, wxr1));
        axr = ta.x + ta.y + brh;
        v2f tb = pk_fma(nx0, wxz0, pk_mul(nx1, wxz1));
        axz = tb.x + tb.y + bzh;
        v2f tc = pk_fma(nx0, wxn0, pk_mul(nx1, wxn1));
        cxn = half_sum(tc.x + tc.y + bxnh);
    }

    // main loop: steps 0..4087 (511 groups of 8), refilling x[s+8] each step
#pragma unroll 1
    for (int s0 = 0; s0 < Tn - 8; s0 += 8) {
        GRU_STEP(x1, x0, true)
        GRU_STEP(x2, x1, true)
        GRU_STEP(x3, x2, true)
        GRU_STEP(x4, x3, true)
        GRU_STEP(x5, x4, true)
        GRU_STEP(x6, x5, true)
        GRU_STEP(x7, x6, true)
        GRU_STEP(x0, x7, true)
    }
    // epilogue: steps 4088..4095, no refills (slots hold x[4088..4095])
    GRU_STEP(x1, x0, false)
    GRU_STEP(x2, x1, false)
    GRU_STEP(x3, x2, false)
    GRU_STEP(x4, x3, false)
    GRU_STEP(x5, x4, false)
    GRU_STEP(x6, x5, false)
    GRU_STEP(x7, x6, false)
    GRU_STEP(x0, x7, false)
}
#undef KEEP

// outputs[b,t,o] = sum_h latents[b,t,h] * E[h,o]
__global__ void decode_kernel(const float* __restrict__ lat,
                              const float* __restrict__ E,
                              float* __restrict__ out) {
    __shared__ float ldsE[Hn * TGTn];
    int tid = threadIdx.x;
    if (tid < Hn * TGTn) ldsE[tid] = E[tid];
    __syncthreads();
    size_t idx = (size_t)blockIdx.x * 256 + tid;   // over B*T*8
    int o      = (int)(idx & (TGTn - 1));
    size_t row = idx >> 3;
    const float* lrow = lat + row * Hn;
    float acc = 0.f;
#pragma unroll
    for (int h = 0; h < Hn; ++h)
        acc = fmaf(lrow[h], ldsE[h * TGTn + o], acc);
    out[idx] = acc;
}

extern "C" void kernel_launch(void* const* d_in, const int* in_sizes, int n_in,
                              void* d_out, int out_size, void* d_ws, size_t ws_size,
                              hipStream_t stream) {
    const float* x    = (const float*)d_in[0];
    const float* E    = (const float*)d_in[1];
    const float* w_ih = (const float*)d_in[2];
    const float* w_hh = (const float*)d_in[3];
    const float* b_ih = (const float*)d_in[4];
    const float* b_hh = (const float*)d_in[5];

    float* out = (float*)d_out;                          // [B,T,8]
    float* lat = out + (size_t)Bsz * Tn * TGTn;          // [B,T,32]
    float* Wf  = (float*)d_ws;                           // [96,8]

    fuse_wih_kernel<<<1, 768, 0, stream>>>(w_ih, E, Wf);
    gru_kernel<<<Bsz, 64, 0, stream>>>(x, Wf, w_hh, b_ih, b_hh, lat);
    decode_kernel<<<(Bsz * Tn * TGTn) / 256, 256, 0, stream>>>(lat, E, out);
}